// Round 7
// baseline (558.120 us; speedup 1.0000x reference)
//
#include <hip/hip_runtime.h>
#include <cmath>

#define TS 2048   // sequence
#define TH 768    // hidden
#define TNH 12    // heads
#define THD 64    // head dim
#define TNF 128   // rff features
#define KC 192    // concat K for scores (64 dot + 128 rff)

typedef __attribute__((ext_vector_type(4))) short s16x4;     // NOTE: 'short4' collides with HIP's vector types
typedef __attribute__((ext_vector_type(8))) short short8;
typedef __attribute__((ext_vector_type(8))) __bf16 bf16x8;   // matches builtin signature V8y
typedef __attribute__((ext_vector_type(4))) float floatx4;

// ---------------- fp32 <-> bf16 helpers ----------------
__device__ __forceinline__ short f2bf(float x) {
    union { float f; unsigned u; } v; v.f = x;
    unsigned r = v.u + 0x7FFFu + ((v.u >> 16) & 1u);   // round-nearest-even
    return (short)(r >> 16);
}
__device__ __forceinline__ float bf2f(short x) {
    union { unsigned u; float f; } v;
    v.u = ((unsigned)(unsigned short)x) << 16;
    return v.f;
}

// ---------------- cvt: fp32 -> bf16 for hs, Wq, Wk, Wv, Wo, omega; job 6 zeroes rowsum ----------------
__global__ __launch_bounds__(256) void k_cvt_bf16(
    const float* __restrict__ s0, const float* __restrict__ s1,
    const float* __restrict__ s2, const float* __restrict__ s3,
    const float* __restrict__ s4, const float* __restrict__ s5,
    short* __restrict__ d0, short* __restrict__ d1,
    short* __restrict__ d2, short* __restrict__ d3,
    short* __restrict__ d4, short* __restrict__ d5,
    float* __restrict__ rowsum) {
    const int y = blockIdx.y;
    if (y == 6) {   // zero the softmax row-sum accumulator (24576 floats)
        for (int i = blockIdx.x * 256 + threadIdx.x; i < TNH * TS / 4; i += gridDim.x * 256)
            ((float4*)rowsum)[i] = (float4){0.f, 0.f, 0.f, 0.f};
        return;
    }
    const float* srcs[6] = {s0, s1, s2, s3, s4, s5};
    short* dsts[6] = {d0, d1, d2, d3, d4, d5};
    const int n4s[6] = {TS * TH / 4, TH * TH / 4, TH * TH / 4, TH * TH / 4,
                        TH * TH / 4, TNH * TNF * THD / 4};
    const float* src = srcs[y];
    short* dst = dsts[y];
    const int n4 = n4s[y];
    for (int i = blockIdx.x * 256 + threadIdx.x; i < n4; i += gridDim.x * 256) {
        float4 v = ((const float4*)src)[i];
        s16x4 o;
        o[0] = f2bf(v.x); o[1] = f2bf(v.y); o[2] = f2bf(v.z); o[3] = f2bf(v.w);
        *(s16x4*)&dst[i * 4] = o;
    }
}

// ---------------- QKV projection (bf16 MFMA) + fused row-norm ----------------
// z==0 (q): Qc[row][0:64] = bf16(0.1125*q); invq[row] = 1/(0.1125*(||q||+1e-5))
// z==1 (k): Kc[row][0:64] = bf16(k);        invk[row] = 1/(||k||+1e-5)
// z==2 (v): Vb[h][d][t] = bf16(v)  (transposed for the PV MFMA B-operand)
__global__ __launch_bounds__(256) void k_proj_qkv_mfma(
    const short* __restrict__ Xb,
    const short* __restrict__ Wqb, const short* __restrict__ Wkb, const short* __restrict__ Wvb,
    const float* __restrict__ b0, const float* __restrict__ b1, const float* __restrict__ b2,
    float* __restrict__ invq, float* __restrict__ invk, short* __restrict__ Vb,
    short* __restrict__ Qc, short* __restrict__ Kc) {
    __shared__ __align__(16) short Asb[128][40];
    __shared__ __align__(16) short Bsb[128][40];
    const int z = blockIdx.z;
    const short* W = (z == 0) ? Wqb : ((z == 1) ? Wkb : Wvb);
    const float* bias = (z == 0) ? b0 : ((z == 1) ? b1 : b2);
    const int n0 = blockIdx.x * 128;
    const int m0 = blockIdx.y * 128;
    const int tid = threadIdx.x;
    const int lane = tid & 63;
    const int w = tid >> 6;
    const int wm = (w >> 1) * 64, wn = (w & 1) * 64;
    const int fr = lane & 15;
    const int quad = lane >> 4;

    floatx4 acc[4][4] = {};

    for (int k0 = 0; k0 < TH; k0 += 32) {
#pragma unroll
        for (int l = 0; l < 2; ++l) {
            int c = tid + l * 256;
            int row = c >> 2, col = (c & 3) << 3;
            *(short8*)&Asb[row][col] = *(const short8*)&Xb[(size_t)(m0 + row) * TH + k0 + col];
            *(short8*)&Bsb[row][col] = *(const short8*)&W[(size_t)(n0 + row) * TH + k0 + col];
        }
        __syncthreads();
        bf16x8 af[4], bfr[4];
#pragma unroll
        for (int i = 0; i < 4; ++i) af[i] = *(const bf16x8*)&Asb[wm + i * 16 + fr][quad * 8];
#pragma unroll
        for (int j = 0; j < 4; ++j) bfr[j] = *(const bf16x8*)&Bsb[wn + j * 16 + fr][quad * 8];
#pragma unroll
        for (int i = 0; i < 4; ++i)
#pragma unroll
            for (int j = 0; j < 4; ++j)
                acc[i][j] = __builtin_amdgcn_mfma_f32_16x16x32_bf16(af[i], bfr[j], acc[i][j], 0, 0, 0);
        __syncthreads();
    }
    // epilogue: C/D layout col=lane&15, row=(lane>>4)*4+reg
    if (z == 2) {
#pragma unroll
        for (int j = 0; j < 4; ++j) {
            int n = n0 + wn + j * 16 + fr;
            int h = n >> 6, d = n & 63;
            float bv = bias[n];
#pragma unroll
            for (int i = 0; i < 4; ++i) {
                int t = m0 + wm + i * 16 + quad * 4;
                s16x4 pk;
#pragma unroll
                for (int r = 0; r < 4; ++r) pk[r] = f2bf(acc[i][j][r] + bv);
                *(s16x4*)&Vb[(size_t)(h * THD + d) * TS + t] = pk;
            }
        }
    } else {
        short* cc = z ? Kc : Qc;
        float* invd = z ? invk : invq;
        const float qs = z ? 1.0f : 0.1125f;
        const int hh = (n0 + wn) >> 6;        // one head per wave
        float ssr[4][4] = {};
#pragma unroll
        for (int j = 0; j < 4; ++j) {
            int n = n0 + wn + j * 16 + fr;
            int d = n & 63;
            float bv = bias[n];
#pragma unroll
            for (int i = 0; i < 4; ++i) {
#pragma unroll
                for (int r = 0; r < 4; ++r) {
                    int m = m0 + wm + i * 16 + quad * 4 + r;
                    float val = acc[i][j][r] + bv;
                    cc[(size_t)(hh * TS + m) * KC + d] = f2bf(val * qs);
                    ssr[i][r] += val * val;
                }
            }
        }
#pragma unroll
        for (int i = 0; i < 4; ++i)
#pragma unroll
            for (int r = 0; r < 4; ++r) {
                float ss = ssr[i][r];
#pragma unroll
                for (int off = 1; off <= 8; off <<= 1) ss += __shfl_xor(ss, off, 64);
                if (fr == 0) {
                    int m = m0 + wm + i * 16 + quad * 4 + r;
                    invd[hh * TS + m] = 1.0f / (qs * (sqrtf(ss) + 1e-5f));
                }
            }
    }
}

// ---------------- output projection (bf16 MFMA): out = ctxb @ Wob^T + bo ----------------
__global__ __launch_bounds__(256) void k_proj_out_mfma(
    const short* __restrict__ ctxb, const short* __restrict__ Wob,
    const float* __restrict__ bias, float* __restrict__ out) {
    __shared__ __align__(16) short Asb[128][40];
    __shared__ __align__(16) short Bsb[128][40];
    const int n0 = blockIdx.x * 128;
    const int m0 = blockIdx.y * 128;
    const int tid = threadIdx.x;
    const int lane = tid & 63;
    const int w = tid >> 6;
    const int wm = (w >> 1) * 64, wn = (w & 1) * 64;
    const int fr = lane & 15;
    const int quad = lane >> 4;

    floatx4 acc[4][4] = {};

    for (int k0 = 0; k0 < TH; k0 += 32) {
#pragma unroll
        for (int l = 0; l < 2; ++l) {
            int c = tid + l * 256;
            int row = c >> 2, col = (c & 3) << 3;
            *(short8*)&Asb[row][col] = *(const short8*)&ctxb[(size_t)(m0 + row) * TH + k0 + col];
            *(short8*)&Bsb[row][col] = *(const short8*)&Wob[(size_t)(n0 + row) * TH + k0 + col];
        }
        __syncthreads();
        bf16x8 af[4], bfr[4];
#pragma unroll
        for (int i = 0; i < 4; ++i) af[i] = *(const bf16x8*)&Asb[wm + i * 16 + fr][quad * 8];
#pragma unroll
        for (int j = 0; j < 4; ++j) bfr[j] = *(const bf16x8*)&Bsb[wn + j * 16 + fr][quad * 8];
#pragma unroll
        for (int i = 0; i < 4; ++i)
#pragma unroll
            for (int j = 0; j < 4; ++j)
                acc[i][j] = __builtin_amdgcn_mfma_f32_16x16x32_bf16(af[i], bfr[j], acc[i][j], 0, 0, 0);
        __syncthreads();
    }
#pragma unroll
    for (int j = 0; j < 4; ++j) {
        int n = n0 + wn + j * 16 + fr;
        float bv = bias[n];
#pragma unroll
        for (int i = 0; i < 4; ++i)
#pragma unroll
            for (int r = 0; r < 4; ++r) {
                int m = m0 + wm + i * 16 + quad * 4 + r;
                out[(size_t)m * TH + n] = acc[i][j][r] + bv;
            }
    }
}

// ---------------- phi (bf16 MFMA) + fused row-L2-normalize ----------------
__global__ __launch_bounds__(256) void k_phi_mfma(
    const float* __restrict__ invq, const float* __restrict__ invk,
    const short* __restrict__ omegab, const float* __restrict__ rffb,
    short* __restrict__ Qc, short* __restrict__ Kc) {
    __shared__ __align__(16) short Asb[128][40];
    __shared__ __align__(16) short Bsb[128][40];
    __shared__ float smP[4][64];
    const int z = blockIdx.y;
    const int h = z >> 1, which = z & 1;
    const float* inv = which ? invk : invq;
    short* buf = which ? Kc : Qc;      // read cols [0:64], write cols [64:192]
    const int m0 = blockIdx.x * 128;
    const int tid = threadIdx.x;
    const int lane = tid & 63;
    const int w = tid >> 6;
    const int wm = (w >> 1) * 64, wn = (w & 1) * 64;
    const int fr = lane & 15;
    const int quad = lane >> 4;

    floatx4 acc[4][4] = {};

    for (int k0 = 0; k0 < THD; k0 += 32) {
#pragma unroll
        for (int l = 0; l < 2; ++l) {
            int c = tid + l * 256;
            int row = c >> 2, col = (c & 3) << 3;
            int rq = h * TS + m0 + row;
            float s = inv[rq];
            short8 a = *(const short8*)&buf[(size_t)rq * KC + k0 + col];
            short8 o;
#pragma unroll
            for (int e = 0; e < 8; ++e) o[e] = f2bf(bf2f(a[e]) * s);
            *(short8*)&Asb[row][col] = o;
            *(short8*)&Bsb[row][col] = *(const short8*)&omegab[(size_t)(h * TNF + row) * THD + k0 + col];
        }
        __syncthreads();
        bf16x8 af[4], bfr[4];
#pragma unroll
        for (int i = 0; i < 4; ++i) af[i] = *(const bf16x8*)&Asb[wm + i * 16 + fr][quad * 8];
#pragma unroll
        for (int j = 0; j < 4; ++j) bfr[j] = *(const bf16x8*)&Bsb[wn + j * 16 + fr][quad * 8];
#pragma unroll
        for (int i = 0; i < 4; ++i)
#pragma unroll
            for (int j = 0; j < 4; ++j)
                acc[i][j] = __builtin_amdgcn_mfma_f32_16x16x32_bf16(af[i], bfr[j], acc[i][j], 0, 0, 0);
        __syncthreads();
    }
    // epilogue: p = 0.125*cos(acc + b) in place; ss over this wave's 64 f, then wave-pair sum
    float bvj[4];
#pragma unroll
    for (int j = 0; j < 4; ++j) bvj[j] = rffb[h * TNF + wn + j * 16 + fr];
    float ssr[4][4] = {};
#pragma unroll
    for (int i = 0; i < 4; ++i)
#pragma unroll
        for (int j = 0; j < 4; ++j)
#pragma unroll
            for (int r = 0; r < 4; ++r) {
                float p = 0.125f * cosf(acc[i][j][r] + bvj[j]);   // SIGMA = 1
                acc[i][j][r] = p;
                ssr[i][r] += p * p;
            }
#pragma unroll
    for (int i = 0; i < 4; ++i)
#pragma unroll
        for (int r = 0; r < 4; ++r) {
#pragma unroll
            for (int off = 1; off <= 8; off <<= 1) ssr[i][r] += __shfl_xor(ssr[i][r], off, 64);
        }
    if (fr == 0) {
#pragma unroll
        for (int i = 0; i < 4; ++i)
#pragma unroll
            for (int r = 0; r < 4; ++r) smP[w][i * 16 + quad * 4 + r] = ssr[i][r];
    }
    __syncthreads();
    const float scale0 = which ? 1.0f : 0.1f;
#pragma unroll
    for (int i = 0; i < 4; ++i)
#pragma unroll
        for (int r = 0; r < 4; ++r) {
            int rl = i * 16 + quad * 4 + r;
            float ss = smP[w][rl] + smP[w ^ 1][rl];
            float sc = scale0 / (sqrtf(ss) + 1e-6f);
            int m = m0 + wm + rl;
#pragma unroll
            for (int j = 0; j < 4; ++j) {
                int f = wn + j * 16 + fr;
                buf[(size_t)(h * TS + m) * KC + 64 + f] = f2bf(acc[i][j][r] * sc);
            }
        }
}

// ---------------- scores + exp + row-sums: writes e^(s+mb) to wout, atomicAdds row sums ----------------
// Max-free softmax is safe here: |dot| <= ||q||*||k||/8*0.9 ~ 15 max (e^15 fine in fp32),
// and masked entries (s-10000) underflow to exactly 0. Sum accumulates the SAME fp32 values
// written to wout, so numerator/denominator are consistent.
__global__ __launch_bounds__(256) void k_scores_mfma(
    const short* __restrict__ Qc, const short* __restrict__ Kc,
    const float* __restrict__ mask, float* __restrict__ wout, float* __restrict__ rowsum) {
    __shared__ __align__(16) short Asb[128][40];   // 80 B row stride: 16B-aligned, <=2-way bank alias
    __shared__ __align__(16) short Bsb[128][40];
    const int h = blockIdx.z;
    const int n0 = blockIdx.x * 128;
    const int m0 = blockIdx.y * 128;
    const int tid = threadIdx.x;
    const int lane = tid & 63;
    const int w = tid >> 6;
    const int wm = (w >> 1) * 64, wn = (w & 1) * 64;
    const int fr = lane & 15;          // fragment row/col within 16
    const int quad = lane >> 4;        // k-quad

    floatx4 acc[4][4] = {};

    for (int k0 = 0; k0 < KC; k0 += 32) {
#pragma unroll
        for (int l = 0; l < 2; ++l) {
            int c = tid + l * 256;
            int row = c >> 2, col = (c & 3) << 3;
            short8 a = *(const short8*)&Qc[(size_t)(h * TS + m0 + row) * KC + k0 + col];
            *(short8*)&Asb[row][col] = a;
            short8 b = *(const short8*)&Kc[(size_t)(h * TS + n0 + row) * KC + k0 + col];
            *(short8*)&Bsb[row][col] = b;
        }
        __syncthreads();
        bf16x8 af[4], bfr[4];
#pragma unroll
        for (int i = 0; i < 4; ++i) af[i] = *(const bf16x8*)&Asb[wm + i * 16 + fr][quad * 8];
#pragma unroll
        for (int j = 0; j < 4; ++j) bfr[j] = *(const bf16x8*)&Bsb[wn + j * 16 + fr][quad * 8];
#pragma unroll
        for (int i = 0; i < 4; ++i)
#pragma unroll
            for (int j = 0; j < 4; ++j)
                acc[i][j] = __builtin_amdgcn_mfma_f32_16x16x32_bf16(af[i], bfr[j], acc[i][j], 0, 0, 0);
        __syncthreads();
    }
    // epilogue: e = exp(s + maskbias); write e; per-row partial sums -> shfl over fr -> atomicAdd
    float mb[4];
#pragma unroll
    for (int j = 0; j < 4; ++j) mb[j] = (mask[n0 + wn + j * 16 + fr] - 1.0f) * 10000.0f;
    float psum[4][4] = {};
#pragma unroll
    for (int j = 0; j < 4; ++j) {
        int col_g = n0 + wn + j * 16 + fr;
#pragma unroll
        for (int i = 0; i < 4; ++i) {
#pragma unroll
            for (int r = 0; r < 4; ++r) {
                int row_g = m0 + wm + i * 16 + quad * 4 + r;
                float e = __expf(acc[i][j][r] + mb[j]);
                wout[(size_t)(h * TS + row_g) * TS + col_g] = e;
                psum[i][r] += e;
            }
        }
    }
#pragma unroll
    for (int i = 0; i < 4; ++i)
#pragma unroll
        for (int r = 0; r < 4; ++r) {
            float p = psum[i][r];
#pragma unroll
            for (int off = 1; off <= 8; off <<= 1) p += __shfl_xor(p, off, 64);
            if (fr == 0)
                atomicAdd(&rowsum[h * TS + m0 + wm + i * 16 + quad * 4 + r], p);
        }
}

// ---------------- context GEMM (bf16 MFMA) + in-place weight normalization ----------------
// A-staging reads e^s from wout, multiplies per-row 1/rowsum, writes the NORMALIZED fp32
// weight back in place (each element touched by exactly one thread) and bf16(w) to LDS.
// Epilogue writes bf16 ctx. Replaces the separate softmax kernel (saves 402 MB traffic).
__global__ __launch_bounds__(256) void k_ctx_mfma(
    float* __restrict__ wout, const float* __restrict__ rowsum,
    const short* __restrict__ Vb, short* __restrict__ ctxb) {
    __shared__ __align__(16) short Asb[128][40];
    __shared__ __align__(16) short Bsb[64][40];
    __shared__ float smR[128];
    const int h = blockIdx.y;
    const int m0 = blockIdx.x * 128;
    const int tid = threadIdx.x;
    const int lane = tid & 63;
    const int w = tid >> 6;
    const int wm = w * 32;             // wave's 32-row strip
    const int fr = lane & 15;
    const int quad = lane >> 4;
    if (tid < 128) smR[tid] = 1.0f / rowsum[h * TS + m0 + tid];
    __syncthreads();
    floatx4 acc[2][4] = {};
    for (int k0 = 0; k0 < TS; k0 += 32) {
        // stage A: 128 rows x 32 t: read e^s, normalize, write back fp32, stage bf16
#pragma unroll
        for (int l = 0; l < 4; ++l) {
            int idx = tid + l * 256;
            int row = idx >> 3, col = (idx & 7) << 2;
            float rin = smR[row];
            size_t base = (size_t)(h * TS + m0 + row) * TS + k0 + col;
            float4 a = *(const float4*)&wout[base];
            float w0 = a.x * rin, w1 = a.y * rin, w2 = a.z * rin, w3 = a.w * rin;
            *(float4*)&wout[base] = (float4){w0, w1, w2, w3};
            s16x4 s;
            s[0] = f2bf(w0); s[1] = f2bf(w1); s[2] = f2bf(w2); s[3] = f2bf(w3);
            *(s16x4*)&Asb[row][col] = s;
        }
        {
            int row = tid >> 2, col = (tid & 3) << 3;
            *(short8*)&Bsb[row][col] =
                *(const short8*)&Vb[(size_t)(h * THD + row) * TS + k0 + col];
        }
        __syncthreads();
        bf16x8 af[2], bfr[4];
#pragma unroll
        for (int i = 0; i < 2; ++i) af[i] = *(const bf16x8*)&Asb[wm + i * 16 + fr][quad * 8];
#pragma unroll
        for (int j = 0; j < 4; ++j) bfr[j] = *(const bf16x8*)&Bsb[j * 16 + fr][quad * 8];
#pragma unroll
        for (int i = 0; i < 2; ++i)
#pragma unroll
            for (int j = 0; j < 4; ++j)
                acc[i][j] = __builtin_amdgcn_mfma_f32_16x16x32_bf16(af[i], bfr[j], acc[i][j], 0, 0, 0);
        __syncthreads();
    }
#pragma unroll
    for (int i = 0; i < 2; ++i)
#pragma unroll
        for (int j = 0; j < 4; ++j)
#pragma unroll
            for (int r = 0; r < 4; ++r) {
                int row_g = m0 + wm + i * 16 + quad * 4 + r;
                ctxb[(size_t)row_g * TH + h * THD + j * 16 + fr] = f2bf(acc[i][j][r]);
            }
}

extern "C" void kernel_launch(void* const* d_in, const int* in_sizes, int n_in,
                              void* d_out, int out_size, void* d_ws, size_t ws_size,
                              hipStream_t stream) {
    const float* hs    = (const float*)d_in[0];
    const float* mask  = (const float*)d_in[1];
    const float* Wq    = (const float*)d_in[2];
    const float* bq    = (const float*)d_in[3];
    const float* Wk    = (const float*)d_in[4];
    const float* bk    = (const float*)d_in[5];
    const float* Wv    = (const float*)d_in[6];
    const float* bv    = (const float*)d_in[7];
    const float* Wo    = (const float*)d_in[8];
    const float* bo    = (const float*)d_in[9];
    const float* omega = (const float*)d_in[10];
    const float* rffb  = (const float*)d_in[11];

    float* out0 = (float*)d_out;               // (S,H) final output
    float* wout = out0 + TS * TH;              // (NH,S,S) attention weights

    // workspace layout (floats); fp32 q/k slots are dead -> rowsum lives at ws+0
    float* ws   = (float*)d_ws;
    float* rowsum = ws;                        // NH*S = 24576 floats (softmax denominators)
    short* Vb   = (short*)(ws + 3145728);      // NH*HD*TS shorts (transposed bf16 V)
    short* Wob  = (short*)(ws + 3932160);      // TH*TH shorts
    short* omegab = (short*)(ws + 4227072);    // NH*TNF*THD shorts
    float* invq = ws + 4718592;                // NH*S
    float* invk = ws + 4743168;
    short* ctxb = (short*)(ws + 4767744);      // S*H shorts
    short* Qc   = (short*)(ws + 6340608);      // NH*S*KC bf16
    short* Kc   = (short*)(ws + 8699904);

    // bf16 staging for the QKV projection, overlaid on wout (k_scores overwrites wout later)
    short* Xb  = (short*)wout;                 // TS*TH shorts
    short* Wqb = Xb + (size_t)TS * TH;
    short* Wkb = Wqb + (size_t)TH * TH;
    short* Wvb = Wkb + (size_t)TH * TH;

    k_cvt_bf16<<<dim3(512, 7), 256, 0, stream>>>(hs, Wq, Wk, Wv, Wo, omega,
                                                 Xb, Wqb, Wkb, Wvb, Wob, omegab, rowsum);
    k_proj_qkv_mfma<<<dim3(6, 16, 3), 256, 0, stream>>>(Xb, Wqb, Wkb, Wvb, bq, bk, bv,
                                                        invq, invk, Vb, Qc, Kc);
    k_phi_mfma<<<dim3(16, 24), 256, 0, stream>>>(invq, invk, omegab, rffb, Qc, Kc);
    k_scores_mfma<<<dim3(16, 16, 12), 256, 0, stream>>>(Qc, Kc, mask, wout, rowsum);
    k_ctx_mfma<<<dim3(16, 12), 256, 0, stream>>>(wout, rowsum, Vb, ctxb);
    k_proj_out_mfma<<<dim3(6, 16), 256, 0, stream>>>(ctxb, Wob, bo, out0);
}